// Round 4
// baseline (264.735 us; speedup 1.0000x reference)
//
#include <hip/hip_runtime.h>
#include <cstddef>
#include <cstdint>

#define NEG_SENT (-1.0e30f)

// =====================================================================
//  W=4096, H=2048, D=768, HID=1024, E=64, CC=64, K=3, SENT_LEN=32, MD=128
//  sent_id[w]=w>>5 -> packed cols s*32+p all valid; eid=off-p+63 in [32,94]
//
//  TRANSPOSED pipeline: every GEMM computes the transposed result so the
//  C-layout (col=lane&15, row=(lane>>4)*4+reg) hands each thread 4
//  consecutive-k values of one column -> b64 frag writes, no scatter.
//    GEMM2': X2^T[n2][p] = sum_k w2[k][n2] * x1[p][k]   (A=w2F, B=staged x1)
//    GEMM3': X3^T[c][p]  = sum_n2 w3[n2][c] * X2^T[n2][p]
//    conv1': Y1^T[o][p]  = sum_{tau,c} c1w[o][c][tau] * X3^T[c][p+tau-1]
//  A/B frag formula (16x16x32 bf16): lane=(m&15)+16*((k>>3)&3), idx=k&7.
//  Weight frag tables are identical to the non-transposed versions.
// =====================================================================

typedef short s8v __attribute__((ext_vector_type(8)));
typedef float f32x4 __attribute__((ext_vector_type(4)));

static __device__ __forceinline__ f32x4 mfma16(s8v a, s8v b, f32x4 c) {
  return __builtin_amdgcn_mfma_f32_16x16x32_bf16(a, b, c, 0, 0, 0);
}
static __device__ __forceinline__ unsigned short f2b(float f) {
  union { float f; unsigned u; } v{f};
  unsigned r = v.u + 0x7FFF + ((v.u >> 16) & 1);
  return (unsigned short)(r >> 16);
}
static __device__ __forceinline__ float b2f(unsigned short u) {
  union { unsigned u; float f; } v{((unsigned)u) << 16};
  return v.f;
}
static __device__ __forceinline__ unsigned pk2(float a, float b) {
#if defined(__gfx950__) && __has_builtin(__builtin_amdgcn_cvt_pk_bf16_f32)
  typedef __bf16 b2t __attribute__((ext_vector_type(2)));
  b2t r = __builtin_amdgcn_cvt_pk_bf16_f32(a, b);
  return __builtin_bit_cast(unsigned, r);
#else
  return (unsigned)f2b(a) | ((unsigned)f2b(b) << 16);
#endif
}
static __device__ __forceinline__ float blo(unsigned u) {
  union { unsigned u; float f; } v{u << 16}; return v.f;
}
static __device__ __forceinline__ float bhi(unsigned u) {
  union { unsigned u; float f; } v{u & 0xffff0000u}; return v.f;
}

// ---------- merged prep kernel ----------
// blocks: [0,1536) cvt_words | [1536,2304) cvt_w1 | [2304,2446) cvt_small
//         [2446,2574) embC
__global__ __launch_bounds__(256) void k_prep(
    const float* __restrict__ words, const float* __restrict__ w1,
    const float* __restrict__ b1, const float* __restrict__ emb,
    const float* __restrict__ w2, const float* __restrict__ w3,
    const float* __restrict__ c1w, s8v* __restrict__ wordsF,
    s8v* __restrict__ w1F, s8v* __restrict__ w2F, s8v* __restrict__ w3F,
    s8v* __restrict__ c1F, float* __restrict__ embC) {
  const int bb = blockIdx.x, t = threadIdx.x;
  __shared__ float se[64];
  if (bb < 1536) {  // words [4096][768] -> A-frag
    const int tid = bb * 256 + t;
    const int lane = tid & 63, ks = (tid >> 6) % 24, mt = tid / 1536;
    const int m = mt * 16 + (lane & 15);
    const int kb = ks * 32 + 8 * (lane >> 4);
    const float* src = words + (size_t)m * 768 + kb;
    const float4 v0 = *reinterpret_cast<const float4*>(src);
    const float4 v1 = *reinterpret_cast<const float4*>(src + 4);
    s8v p;
    p[0] = (short)f2b(v0.x); p[1] = (short)f2b(v0.y);
    p[2] = (short)f2b(v0.z); p[3] = (short)f2b(v0.w);
    p[4] = (short)f2b(v1.x); p[5] = (short)f2b(v1.y);
    p[6] = (short)f2b(v1.z); p[7] = (short)f2b(v1.w);
    wordsF[tid] = p;
  } else if (bb < 2304) {  // w1 -> B-frag (N=2048 combined)
    const int tid = (bb - 1536) * 256 + t;
    const int lane = tid & 63, ks = (tid >> 6) % 24, nt = tid / 1536;
    const int n = nt * 16 + (lane & 15);
    const int kb = ks * 32 + 8 * (lane >> 4);
    const int z = n >> 10, col = n & 1023;
    const float* src = w1 + (size_t)(z * 768 + kb) * 1024 + col;
    s8v p;
#pragma unroll
    for (int j = 0; j < 8; ++j) p[j] = (short)f2b(src[(size_t)j * 1024]);
    w1F[tid] = p;
  } else if (bb < 2446) {  // small weights
    const int b = bb - 2304;
    if (b < 128) {  // w2 [1024][256] -> [16 nt][32 ks][64][8]
      const int tid = b * 256 + t;
      const int lane = tid & 63, ks = (tid >> 6) % 32, nt = tid / 2048;
      const int n = nt * 16 + (lane & 15);
      const int kb = ks * 32 + 8 * (lane >> 4);
      s8v p;
#pragma unroll
      for (int j = 0; j < 8; ++j) p[j] = (short)f2b(w2[(size_t)(kb + j) * 256 + n]);
      w2F[tid] = p;
    } else if (b < 136) {  // w3 [256][64] -> [4 nt][8 ks][64][8]
      const int tid = (b - 128) * 256 + t;
      const int lane = tid & 63, ks = (tid >> 6) % 8, nt = tid / 512;
      const int n = nt * 16 + (lane & 15);
      const int kb = ks * 32 + 8 * (lane >> 4);
      s8v p;
#pragma unroll
      for (int j = 0; j < 8; ++j) p[j] = (short)f2b(w3[(size_t)(kb + j) * 64 + n]);
      w3F[tid] = p;
    } else {  // c1w [64][64][3] -> [4 nt][6 ks][64][8], k=tap*64+c
      const int tid = (b - 136) * 256 + t;
      const int lane = tid & 63, ks = (tid >> 6) % 6, nt = tid / 384;
      const int o = nt * 16 + (lane & 15);
      const int kb = ks * 32 + 8 * (lane >> 4);
      s8v p;
#pragma unroll
      for (int j = 0; j < 8; ++j) {
        const int k = kb + j, tap = k >> 6, c = k & 63;
        p[j] = (short)f2b(c1w[(size_t)(o * 64 + c) * 3 + tap]);
      }
      c1F[tid] = p;
    }
  } else {  // embC[e] = emb_table[e] @ w1[1536:1600,:] + b1 (fp32)
    const int e = bb - 2446;
    if (t < 64) se[t] = emb[e * 64 + t];
    __syncthreads();
    float4 acc = *reinterpret_cast<const float4*>(b1 + 4 * t);
#pragma unroll 8
    for (int d = 0; d < 64; ++d) {
      const float4 wv =
          *reinterpret_cast<const float4*>(w1 + (size_t)(1536 + d) * 1024 + 4 * t);
      const float a = se[d];
      acc.x += a * wv.x; acc.y += a * wv.y; acc.z += a * wv.z; acc.w += a * wv.w;
    }
    *reinterpret_cast<float4*>(embC + (size_t)e * 1024 + 4 * t) = acc;
  }
}

// ---------- GEMM1: AWb[4096][2048] bf16 = words @ [w1h | w1w] ----------
__global__ __launch_bounds__(256) void k_gemm1b(const s8v* __restrict__ AF,
                                                const s8v* __restrict__ BF,
                                                unsigned short* __restrict__ AWb) {
  const int t = threadIdx.x, lane = t & 63, w = t >> 6;
  const int mq = w & 1, nq = w >> 1;
  const int mt0 = blockIdx.y * 8 + mq * 4;
  const int nt0 = blockIdx.x * 8 + nq * 4;
  f32x4 acc[4][4] = {};
  const s8v* Ab = AF + (size_t)mt0 * 24 * 64 + lane;
  const s8v* Bb = BF + (size_t)nt0 * 24 * 64 + lane;
#pragma unroll 2
  for (int ks = 0; ks < 24; ++ks) {
    s8v a[4], bx[4];
#pragma unroll
    for (int i = 0; i < 4; ++i) a[i] = Ab[(size_t)(i * 24 + ks) * 64];
#pragma unroll
    for (int j = 0; j < 4; ++j) bx[j] = Bb[(size_t)(j * 24 + ks) * 64];
#pragma unroll
    for (int i = 0; i < 4; ++i)
#pragma unroll
      for (int j = 0; j < 4; ++j) acc[i][j] = mfma16(a[i], bx[j], acc[i][j]);
  }
  const int rl = (lane >> 4) * 4, cl = lane & 15;
#pragma unroll
  for (int i = 0; i < 4; ++i)
#pragma unroll
    for (int j = 0; j < 4; ++j) {
      const int n = (nt0 + j) * 16 + cl;
#pragma unroll
      for (int r = 0; r < 4; ++r) {
        const int m = (mt0 + i) * 16 + rl + r;
        AWb[(size_t)m * 2048 + n] = f2b(acc[i][j][r]);
      }
    }
}

// ---------- fused per-2-head block, transposed pipeline ----------
__global__ __launch_bounds__(256, 3) void k_fused(
    const int* __restrict__ heads, const unsigned short* __restrict__ AWb,
    const float* __restrict__ embC, const s8v* __restrict__ w2F,
    const float* __restrict__ b2, const s8v* __restrict__ w3F,
    const float* __restrict__ b3, const s8v* __restrict__ c1F,
    const float* __restrict__ c1b, const float* __restrict__ c2w,
    const float* __restrict__ c2b, float* __restrict__ out) {
  const int h0 = blockIdx.x * 2;
  const int t = threadIdx.x, lane = t & 63, w = t >> 6;
  const int q = lane >> 4, cl = lane & 15;
  const int hidA = heads[h0], hidB = heads[h0 + 1];
  const int sA_ = hidA >> 5, offA = hidA & 31;
  const int sB_ = hidB >> 5, offB = hidB & 31;

  __shared__ float sHead[2][1024];                  // 8 KB
  __shared__ __align__(16) char regA[32768];        // aliased phase region
  s8v (*sB1)[4][64] = reinterpret_cast<s8v(*)[4][64]>(regA);    // staging frags
  s8v (*sX2f)[8][64] = reinterpret_cast<s8v(*)[8][64]>(regA);   // X2^T B-frags
  s8v (*sCv)[6][64] = reinterpret_cast<s8v(*)[6][64]>(regA);    // conv B-frags
  float* sY1 = reinterpret_cast<float*>(regA);                  // [64][68] fp32
  ushort* sX2u = reinterpret_cast<ushort*>(regA);

  // sentinel fill of both heads' output rows
  {
    float4 m4; m4.x = m4.y = m4.z = m4.w = NEG_SENT;
    float4* o0 = reinterpret_cast<float4*>(out + (size_t)h0 * 8192);
    float4* o1 = reinterpret_cast<float4*>(out + (size_t)(h0 + 1) * 8192);
#pragma unroll
    for (int i = 0; i < 8; ++i) {
      const int fi = t + (i << 8);
      if ((fi >> 4) != sA_) o0[fi] = m4;
      if ((fi >> 4) != sB_) o1[fi] = m4;
    }
  }

  // head rows (AWb[hid][0:1024] bf16 -> fp32 LDS)
  {
    const ushort4 ha = *reinterpret_cast<const ushort4*>(AWb + (size_t)hidA * 2048 + 4 * t);
    const ushort4 hb = *reinterpret_cast<const ushort4*>(AWb + (size_t)hidB * 2048 + 4 * t);
    float4 fa; fa.x = b2f(ha.x); fa.y = b2f(ha.y); fa.z = b2f(ha.z); fa.w = b2f(ha.w);
    float4 fb; fb.x = b2f(hb.x); fb.y = b2f(hb.y); fb.z = b2f(hb.z); fb.w = b2f(hb.w);
    *reinterpret_cast<float4*>(&sHead[0][4 * t]) = fa;
    *reinterpret_cast<float4*>(&sHead[1][4 * t]) = fb;
  }

  // staging coords: thread covers x1 row p'=t>>2, k-chunk kb32=(t&3)*32
  const int pprime = t >> 2;                // 0..63 (2 heads x 32 pos)
  const int kb32 = (t & 3) * 32;
  const int headS = pprime >> 5, posS = pprime & 31;
  const int hidS = headS ? hidB : hidA;
  const int offS = hidS & 31;
  const int eidp = offS - posS + 63;        // [32,94]
  const unsigned short* wrow =
      AWb + (size_t)((hidS >> 5) * 32 + posS) * 2048 + 1024 + kb32;
  const float* erow = embC + (size_t)eidp * 1024 + kb32;
  const float* hrow = &sHead[headS][kb32];
  const int ntp0 = pprime >> 4, ksS = t & 3, l0 = pprime & 15;

  f32x4 acc[4][4] = {};  // [i: n2-tile][ntp: p'-tile]

  for (int j0 = 0; j0 < 1024; j0 += 128) {
    __syncthreads();
    // stage x1 chunk as B-frags: value x1[p'][k] -> slot(k, col=p')
#pragma unroll
    for (int g = 0; g < 4; ++g) {
      const uint4 wv = *reinterpret_cast<const uint4*>(wrow + j0 + 8 * g);
      const float4 e0 = *reinterpret_cast<const float4*>(erow + j0 + 8 * g);
      const float4 e1 = *reinterpret_cast<const float4*>(erow + j0 + 8 * g + 4);
      const float4 g0 = *reinterpret_cast<const float4*>(hrow + j0 + 8 * g);
      const float4 g1 = *reinterpret_cast<const float4*>(hrow + j0 + 8 * g + 4);
      uint4 r;
      r.x = pk2(fmaxf(blo(wv.x) + e0.x + g0.x, 0.f),
                fmaxf(bhi(wv.x) + e0.y + g0.y, 0.f));
      r.y = pk2(fmaxf(blo(wv.y) + e0.z + g0.z, 0.f),
                fmaxf(bhi(wv.y) + e0.w + g0.w, 0.f));
      r.z = pk2(fmaxf(blo(wv.z) + e1.x + g1.x, 0.f),
                fmaxf(bhi(wv.z) + e1.y + g1.y, 0.f));
      r.w = pk2(fmaxf(blo(wv.w) + e1.z + g1.z, 0.f),
                fmaxf(bhi(wv.w) + e1.w + g1.w, 0.f));
      *reinterpret_cast<uint4*>(&sB1[ntp0][ksS][l0 + 16 * g]) = r;
    }
    __syncthreads();

    const int ksg0 = j0 >> 5;
#pragma unroll
    for (int ks2 = 0; ks2 < 4; ++ks2) {
      s8v bv[4], av[4];
#pragma unroll
      for (int ntp = 0; ntp < 4; ++ntp) bv[ntp] = sB1[ntp][ks2][lane];
#pragma unroll
      for (int i = 0; i < 4; ++i)
        av[i] = w2F[(size_t)((w * 4 + i) * 32 + ksg0 + ks2) * 64 + lane];
#pragma unroll
      for (int i = 0; i < 4; ++i)
#pragma unroll
        for (int ntp = 0; ntp < 4; ++ntp)
          acc[i][ntp] = mfma16(av[i], bv[ntp], acc[i][ntp]);
    }
  }
  __syncthreads();  // sB1 dead; sX2f overlaps it

  // GEMM2' epilogue: X2^T = relu(acc + b2) -> B-frags for GEMM3'
#pragma unroll
  for (int i = 0; i < 4; ++i) {
    const int n2b = w * 64 + i * 16 + q * 4;      // 4 consecutive n2
    const float4 bb = *reinterpret_cast<const float4*>(b2 + n2b);
    const int ks3 = n2b >> 5, g3 = (n2b >> 3) & 3, idx0 = n2b & 7;
#pragma unroll
    for (int ntp = 0; ntp < 4; ++ntp) {
      const unsigned u0 = pk2(fmaxf(acc[i][ntp][0] + bb.x, 0.f),
                              fmaxf(acc[i][ntp][1] + bb.y, 0.f));
      const unsigned u1 = pk2(fmaxf(acc[i][ntp][2] + bb.z, 0.f),
                              fmaxf(acc[i][ntp][3] + bb.w, 0.f));
      uint2 uu; uu.x = u0; uu.y = u1;
      *reinterpret_cast<uint2*>(
          sX2u + (((size_t)ntp * 8 + ks3) * 64 + cl + 16 * g3) * 8 + idx0) = uu;
    }
  }
  __syncthreads();

  // GEMM3': X3^T[c][p'] ; wave w -> c-tile w
  f32x4 acc3[4] = {};
#pragma unroll
  for (int ks3 = 0; ks3 < 8; ++ks3) {
    const s8v a = w3F[(size_t)(w * 8 + ks3) * 64 + lane];
#pragma unroll
    for (int ntp = 0; ntp < 4; ++ntp)
      acc3[ntp] = mfma16(a, sX2f[ntp][ks3][lane], acc3[ntp]);
  }
  __syncthreads();  // sX2f dead; conv region overlaps

  // zero conv frag region (24 KB)
  {
    uint4 z; z.x = z.y = z.z = z.w = 0;
    uint4* zp = reinterpret_cast<uint4*>(regA);
#pragma unroll
    for (int i2 = 0; i2 < 6; ++i2) zp[t + 256 * i2] = z;
  }
  __syncthreads();

  // conv1' im2col frag writes: X3^T(c quad, p') -> slots (k=tau*64+c, col=p'+1-tau)
  {
    const int cb = 16 * w + q * 4;
    const float4 b3v = *reinterpret_cast<const float4*>(b3 + cb);
    const int gC = (cb >> 3) & 3, idx0 = cb & 7, ksb = cb >> 5;  // ksb = w>>1
#pragma unroll
    for (int ntp = 0; ntp < 4; ++ntp) {
      const int pp = ntp * 16 + cl, hd = pp >> 5, pos = pp & 31;
      const unsigned u0 = pk2(acc3[ntp][0] + b3v.x, acc3[ntp][1] + b3v.y);
      const unsigned u1 = pk2(acc3[ntp][2] + b3v.z, acc3[ntp][3] + b3v.w);
      uint2 uu; uu.x = u0; uu.y = u1;
#pragma unroll
      for (int tau = 0; tau < 3; ++tau) {
        const int pt = pos + 1 - tau;
        if ((unsigned)pt < 32u) {
          const int ppt = hd * 32 + pt;
          const int ks = 2 * tau + ksb;
          *reinterpret_cast<uint2*>(
              sX2u + (((size_t)(ppt >> 4) * 6 + ks) * 64 + (ppt & 15) + 16 * gC) * 8 +
              idx0) = uu;
        }
      }
    }
  }
  __syncthreads();

  // conv1' MFMA: Y1^T[o][p'] ; wave w -> o-tile w
  f32x4 accc[4] = {};
#pragma unroll
  for (int ks = 0; ks < 6; ++ks) {
    const s8v a = c1F[(size_t)(w * 6 + ks) * 64 + lane];
#pragma unroll
    for (int ntp = 0; ntp < 4; ++ntp)
      accc[ntp] = mfma16(a, sCv[ntp][ks][lane], accc[ntp]);
  }
  __syncthreads();  // sCv dead; sY1 overlaps

  // Y1^T -> fp32 LDS [64 o][68] with per-head zero pad cols (0,33,34,67)
  {
    const int o = t >> 2, pc = t & 3;
    const int colz = (pc == 0) ? 0 : (pc == 1) ? 33 : (pc == 2) ? 34 : 67;
    sY1[o * 68 + colz] = 0.f;
  }
  {
    const int ob = 16 * w + q * 4;
    const float4 cbv = *reinterpret_cast<const float4*>(c1b + ob);
#pragma unroll
    for (int ntp = 0; ntp < 4; ++ntp) {
      const int pp = ntp * 16 + cl, hd = pp >> 5, pos = pp & 31;
      const int col = hd * 34 + 1 + pos;
      sY1[(ob + 0) * 68 + col] = accc[ntp][0] + cbv.x;
      sY1[(ob + 1) * 68 + col] = accc[ntp][1] + cbv.y;
      sY1[(ob + 2) * 68 + col] = accc[ntp][2] + cbv.z;
      sY1[(ob + 3) * 68 + col] = accc[ntp][3] + cbv.w;
    }
  }
  __syncthreads();

  // conv2 (64ch*3tap -> 2) on VALU, K split 2 ways + shuffle reduce, scatter
  {
    const int kq = t & 1, c2 = (t >> 1) & 1, pp = t >> 2;
    const int hd = pp >> 5, pos = pp & 31, col = hd * 34 + 1 + pos;
    float a2 = 0.f;
    const float* wp = c2w + (size_t)(c2 * 64 + kq * 32) * 3;
    const float* yb = sY1 + (size_t)(kq * 32) * 68 + col;
#pragma unroll
    for (int o = 0; o < 32; ++o) {
      a2 += yb[o * 68 - 1] * wp[o * 3 + 0] + yb[o * 68] * wp[o * 3 + 1] +
            yb[o * 68 + 1] * wp[o * 3 + 2];
    }
    a2 += __shfl_xor(a2, 1, 64);
    if (kq == 0) {
      const int hidR = hd ? hidB : hidA;
      const int sR = hidR >> 5, offR = hidR & 31;
      const int rel = offR - pos;
      const bool ok = (c2 == 0) ? (rel >= 0) : (rel <= 0);
      out[(size_t)(h0 + hd) * 8192 + (size_t)(sR * 32 + pos) * 2 + c2] =
          ok ? (a2 + c2b[c2]) : NEG_SENT;
    }
  }
}

extern "C" void kernel_launch(void* const* d_in, const int* in_sizes, int n_in,
                              void* d_out, int out_size, void* d_ws,
                              size_t ws_size, hipStream_t stream) {
  const float* words = (const float*)d_in[1];
  const int* heads = (const int*)d_in[2];
  const float* emb = (const float*)d_in[3];
  const float* w1 = (const float*)d_in[4];
  const float* b1 = (const float*)d_in[5];
  const float* w2 = (const float*)d_in[6];
  const float* b2 = (const float*)d_in[7];
  const float* w3 = (const float*)d_in[8];
  const float* b3 = (const float*)d_in[9];
  const float* c1w = (const float*)d_in[10];
  const float* c1b = (const float*)d_in[11];
  const float* c2w = (const float*)d_in[12];
  const float* c2b = (const float*)d_in[13];
  float* out = (float*)d_out;

  char* ws = (char*)d_ws;
  float* embC = (float*)ws;                         ws += 128 * 1024 * 4;
  unsigned short* AWb = (unsigned short*)ws;        ws += 4096 * 2048 * 2;
  s8v* wordsF = (s8v*)ws;                           ws += 393216 * 16;
  s8v* w1F = (s8v*)ws;                              ws += 196608 * 16;
  s8v* w2F = (s8v*)ws;                              ws += 32768 * 16;
  s8v* w3F = (s8v*)ws;                              ws += 2048 * 16;
  s8v* c1F = (s8v*)ws;                              ws += 1536 * 16;

  k_prep<<<2574, 256, 0, stream>>>(words, w1, b1, emb, w2, w3, c1w, wordsF,
                                   w1F, w2F, w3F, c1F, embC);
  k_gemm1b<<<dim3(16, 32), 256, 0, stream>>>(wordsF, w1F, AWb);
  k_fused<<<1024, 256, 0, stream>>>(heads, AWb, embC, w2F, b2, w3F, b3, c1F,
                                    c1b, c2w, c2b, out);
}

// Round 5
// 215.216 us; speedup vs baseline: 1.2301x; 1.2301x over previous
//
#include <hip/hip_runtime.h>
#include <cstddef>
#include <cstdint>

#define NEG_SENT (-1.0e30f)

// =====================================================================
//  W=4096, H=2048, D=768, HID=1024, E=64, CC=64, K=3, SENT_LEN=32, MD=128
//  sent_id[w]=w>>5 -> packed cols s*32+p all valid; eid=off-p+63 in [32,94]
//
//  TRANSPOSED pipeline (see R4). This round: double-buffered x1 staging
//  (1 barrier/chunk), conflict-free ds_write_b128 slots, bf16 embC/sHead,
//  register-prefetched GEMM1, small-weight conversions folded into the
//  GEMM1 launch to overlap.
// =====================================================================

typedef short s8v __attribute__((ext_vector_type(8)));
typedef float f32x4 __attribute__((ext_vector_type(4)));

static __device__ __forceinline__ f32x4 mfma16(s8v a, s8v b, f32x4 c) {
  return __builtin_amdgcn_mfma_f32_16x16x32_bf16(a, b, c, 0, 0, 0);
}
static __device__ __forceinline__ unsigned short f2b(float f) {
  union { float f; unsigned u; } v{f};
  unsigned r = v.u + 0x7FFF + ((v.u >> 16) & 1);
  return (unsigned short)(r >> 16);
}
static __device__ __forceinline__ unsigned pk2(float a, float b) {
#if defined(__gfx950__) && __has_builtin(__builtin_amdgcn_cvt_pk_bf16_f32)
  typedef __bf16 b2t __attribute__((ext_vector_type(2)));
  b2t r = __builtin_amdgcn_cvt_pk_bf16_f32(a, b);
  return __builtin_bit_cast(unsigned, r);
#else
  return (unsigned)f2b(a) | ((unsigned)f2b(b) << 16);
#endif
}
static __device__ __forceinline__ float blo(unsigned u) {
  union { unsigned u; float f; } v{u << 16}; return v.f;
}
static __device__ __forceinline__ float bhi(unsigned u) {
  union { unsigned u; float f; } v{u & 0xffff0000u}; return v.f;
}

// ---------- prep1: words -> A-frags (1536 blocks), w1 -> B-frags (768) -------
__global__ __launch_bounds__(256) void k_prep1(const float* __restrict__ words,
                                               const float* __restrict__ w1,
                                               s8v* __restrict__ wordsF,
                                               s8v* __restrict__ w1F) {
  const int bb = blockIdx.x, t = threadIdx.x;
  if (bb < 1536) {  // words [4096][768] -> A-frag
    const int tid = bb * 256 + t;
    const int lane = tid & 63, ks = (tid >> 6) % 24, mt = tid / 1536;
    const int m = mt * 16 + (lane & 15);
    const int kb = ks * 32 + 8 * (lane >> 4);
    const float* src = words + (size_t)m * 768 + kb;
    const float4 v0 = *reinterpret_cast<const float4*>(src);
    const float4 v1 = *reinterpret_cast<const float4*>(src + 4);
    s8v p;
    p[0] = (short)f2b(v0.x); p[1] = (short)f2b(v0.y);
    p[2] = (short)f2b(v0.z); p[3] = (short)f2b(v0.w);
    p[4] = (short)f2b(v1.x); p[5] = (short)f2b(v1.y);
    p[6] = (short)f2b(v1.z); p[7] = (short)f2b(v1.w);
    wordsF[tid] = p;
  } else {  // w1 -> B-frag (N=2048 combined: z=n>>10 selects head/word half)
    const int tid = (bb - 1536) * 256 + t;
    const int lane = tid & 63, ks = (tid >> 6) % 24, nt = tid / 1536;
    const int n = nt * 16 + (lane & 15);
    const int kb = ks * 32 + 8 * (lane >> 4);
    const int z = n >> 10, col = n & 1023;
    const float* src = w1 + (size_t)(z * 768 + kb) * 1024 + col;
    s8v p;
#pragma unroll
    for (int j = 0; j < 8; ++j) p[j] = (short)f2b(src[(size_t)j * 1024]);
    w1F[tid] = p;
  }
}

// ---------- GEMM1 (blocks 0..511) + small cvt (512..653) + embC (654..781) ---
__global__ __launch_bounds__(256) void k_g1(
    const s8v* __restrict__ AF, const s8v* __restrict__ BF,
    unsigned short* __restrict__ AWb, const float* __restrict__ w1,
    const float* __restrict__ b1, const float* __restrict__ emb,
    const float* __restrict__ w2, const float* __restrict__ w3,
    const float* __restrict__ c1w, s8v* __restrict__ w2F,
    s8v* __restrict__ w3F, s8v* __restrict__ c1F,
    unsigned short* __restrict__ embCb) {
  const int bx = blockIdx.x, t = threadIdx.x;
  __shared__ float se[64];
  if (bx < 512) {
    const int lane = t & 63, w = t >> 6;
    const int mq = w & 1, nq = w >> 1;
    const int mt0 = (bx >> 4) * 8 + mq * 4;
    const int nt0 = (bx & 15) * 8 + nq * 4;
    f32x4 acc[4][4] = {};
    const s8v* Ab = AF + (size_t)mt0 * 24 * 64 + lane;
    const s8v* Bb = BF + (size_t)nt0 * 24 * 64 + lane;
    s8v a0[4], b0[4], a1[4], b1v[4];
#pragma unroll
    for (int i = 0; i < 4; ++i) {
      a0[i] = Ab[(size_t)(i * 24) * 64];
      b0[i] = Bb[(size_t)(i * 24) * 64];
    }
#pragma unroll
    for (int ks = 0; ks < 24; ks += 2) {
#pragma unroll
      for (int i = 0; i < 4; ++i) {
        a1[i] = Ab[(size_t)(i * 24 + ks + 1) * 64];
        b1v[i] = Bb[(size_t)(i * 24 + ks + 1) * 64];
      }
#pragma unroll
      for (int i = 0; i < 4; ++i)
#pragma unroll
        for (int j = 0; j < 4; ++j) acc[i][j] = mfma16(a0[i], b0[j], acc[i][j]);
      if (ks + 2 < 24) {
#pragma unroll
        for (int i = 0; i < 4; ++i) {
          a0[i] = Ab[(size_t)(i * 24 + ks + 2) * 64];
          b0[i] = Bb[(size_t)(i * 24 + ks + 2) * 64];
        }
      }
#pragma unroll
      for (int i = 0; i < 4; ++i)
#pragma unroll
        for (int j = 0; j < 4; ++j) acc[i][j] = mfma16(a1[i], b1v[j], acc[i][j]);
    }
    const int rl = (lane >> 4) * 4, cl = lane & 15;
#pragma unroll
    for (int i = 0; i < 4; ++i)
#pragma unroll
      for (int j = 0; j < 4; ++j) {
        const int n = (nt0 + j) * 16 + cl;
#pragma unroll
        for (int r = 0; r < 4; ++r) {
          const int m = (mt0 + i) * 16 + rl + r;
          AWb[(size_t)m * 2048 + n] = f2b(acc[i][j][r]);
        }
      }
  } else if (bx < 654) {  // small weights -> B-frags
    const int b = bx - 512;
    if (b < 128) {  // w2 [1024][256] -> [16 nt][32 ks][64][8]
      const int tid = b * 256 + t;
      const int lane = tid & 63, ks = (tid >> 6) % 32, nt = tid / 2048;
      const int n = nt * 16 + (lane & 15);
      const int kb = ks * 32 + 8 * (lane >> 4);
      s8v p;
#pragma unroll
      for (int j = 0; j < 8; ++j) p[j] = (short)f2b(w2[(size_t)(kb + j) * 256 + n]);
      w2F[tid] = p;
    } else if (b < 136) {  // w3 [256][64] -> [4 nt][8 ks][64][8]
      const int tid = (b - 128) * 256 + t;
      const int lane = tid & 63, ks = (tid >> 6) % 8, nt = tid / 512;
      const int n = nt * 16 + (lane & 15);
      const int kb = ks * 32 + 8 * (lane >> 4);
      s8v p;
#pragma unroll
      for (int j = 0; j < 8; ++j) p[j] = (short)f2b(w3[(size_t)(kb + j) * 64 + n]);
      w3F[tid] = p;
    } else {  // c1w [64][64][3] -> [4 nt][6 ks][64][8], k=tap*64+c
      const int tid = (b - 136) * 256 + t;
      const int lane = tid & 63, ks = (tid >> 6) % 6, nt = tid / 384;
      const int o = nt * 16 + (lane & 15);
      const int kb = ks * 32 + 8 * (lane >> 4);
      s8v p;
#pragma unroll
      for (int j = 0; j < 8; ++j) {
        const int k = kb + j, tap = k >> 6, c = k & 63;
        p[j] = (short)f2b(c1w[(size_t)(o * 64 + c) * 3 + tap]);
      }
      c1F[tid] = p;
    }
  } else {  // embCb[e] = bf16(emb[e] @ w1[1536:1600,:] + b1)
    const int e = bx - 654;
    if (t < 64) se[t] = emb[e * 64 + t];
    __syncthreads();
    float4 acc = *reinterpret_cast<const float4*>(b1 + 4 * t);
#pragma unroll 8
    for (int d = 0; d < 64; ++d) {
      const float4 wv =
          *reinterpret_cast<const float4*>(w1 + (size_t)(1536 + d) * 1024 + 4 * t);
      const float a = se[d];
      acc.x += a * wv.x; acc.y += a * wv.y; acc.z += a * wv.z; acc.w += a * wv.w;
    }
    uint2 r; r.x = pk2(acc.x, acc.y); r.y = pk2(acc.z, acc.w);
    *reinterpret_cast<uint2*>(embCb + (size_t)e * 1024 + 4 * t) = r;
  }
}

// ---------- fused per-2-head block, dbuf-pipelined transposed pipeline -------
__global__ __launch_bounds__(256, 3) void k_fused(
    const int* __restrict__ heads, const unsigned short* __restrict__ AWb,
    const unsigned short* __restrict__ embCb, const s8v* __restrict__ w2F,
    const float* __restrict__ b2, const s8v* __restrict__ w3F,
    const float* __restrict__ b3, const s8v* __restrict__ c1F,
    const float* __restrict__ c1b, const float* __restrict__ c2w,
    const float* __restrict__ c2b, float* __restrict__ out) {
  const int h0 = blockIdx.x * 2;
  const int t = threadIdx.x, lane = t & 63, w = t >> 6;
  const int q = lane >> 4, cl = lane & 15;
  const int hidA = heads[h0], hidB = heads[h0 + 1];
  const int sA_ = hidA >> 5;
  const int sB_ = hidB >> 5;

  __shared__ unsigned short sHead[2][1024];          // bf16, 4 KB
  __shared__ __align__(16) char rgn[2 * 4 * 4 * 64 * 16];  // 32 KB dbuf/tail
  // sB1 slot (16B units): ((buf*4+ntp)*4+ks)*64 + lane
  s8v* sB1 = reinterpret_cast<s8v*>(rgn);
  s8v (*sX2f)[8][64] = reinterpret_cast<s8v(*)[8][64]>(rgn);
  s8v (*sCv)[6][64] = reinterpret_cast<s8v(*)[6][64]>(rgn);
  float* sY1 = reinterpret_cast<float*>(rgn);
  ushort* sX2u = reinterpret_cast<ushort*>(rgn);

  // sentinel fill of both heads' output rows
  {
    float4 m4; m4.x = m4.y = m4.z = m4.w = NEG_SENT;
    float4* o0 = reinterpret_cast<float4*>(out + (size_t)h0 * 8192);
    float4* o1 = reinterpret_cast<float4*>(out + (size_t)(h0 + 1) * 8192);
#pragma unroll
    for (int i = 0; i < 8; ++i) {
      const int fi = t + (i << 8);
      if ((fi >> 4) != sA_) o0[fi] = m4;
      if ((fi >> 4) != sB_) o1[fi] = m4;
    }
  }

  // head rows: AWb[hid][0:1024] bf16 -> LDS (raw)
  {
    const uint2 ha = *reinterpret_cast<const uint2*>(AWb + (size_t)hidA * 2048 + 4 * t);
    const uint2 hb = *reinterpret_cast<const uint2*>(AWb + (size_t)hidB * 2048 + 4 * t);
    *reinterpret_cast<uint2*>(&sHead[0][4 * t]) = ha;
    *reinterpret_cast<uint2*>(&sHead[1][4 * t]) = hb;
  }

  // staging coords: p' = w*16+cl (row), k-quarter q (32 k per chunk-quarter)
  const int pprime = w * 16 + cl;
  const int headS = w >> 1;                // uniform per wave
  const int posS = pprime & 31;
  const int hidS = headS ? hidB : hidA;
  const int offS = hidS & 31;
  const int eidp = offS - posS + 63;       // [32,94]
  const unsigned short* wbase =
      AWb + (size_t)((hidS >> 5) * 32 + posS) * 2048 + 1024 + q * 32;
  const unsigned short* ebase = embCb + (size_t)eidp * 1024 + q * 32;
  const int hbase = headS * 1024 + q * 32;

  uint4 pw[4], pe[4];
#pragma unroll
  for (int g = 0; g < 4; ++g) {
    pw[g] = *reinterpret_cast<const uint4*>(wbase + 8 * g);
    pe[g] = *reinterpret_cast<const uint4*>(ebase + 8 * g);
  }
  __syncthreads();  // sHead visible

  f32x4 acc[4][4] = {};  // [i: n2-tile][ntp: p'-tile]

  // stage chunk0 into buf0
#pragma unroll
  for (int g = 0; g < 4; ++g) {
    const uint4 hv = *reinterpret_cast<const uint4*>(&sHead[0][0] + hbase + 8 * g);
    uint4 r;
    r.x = pk2(fmaxf(blo(pw[g].x) + blo(pe[g].x) + blo(hv.x), 0.f),
              fmaxf(bhi(pw[g].x) + bhi(pe[g].x) + bhi(hv.x), 0.f));
    r.y = pk2(fmaxf(blo(pw[g].y) + blo(pe[g].y) + blo(hv.y), 0.f),
              fmaxf(bhi(pw[g].y) + bhi(pe[g].y) + bhi(hv.y), 0.f));
    r.z = pk2(fmaxf(blo(pw[g].z) + blo(pe[g].z) + blo(hv.z), 0.f),
              fmaxf(bhi(pw[g].z) + bhi(pe[g].z) + bhi(hv.z), 0.f));
    r.w = pk2(fmaxf(blo(pw[g].w) + blo(pe[g].w) + blo(hv.w), 0.f),
              fmaxf(bhi(pw[g].w) + bhi(pe[g].w) + bhi(hv.w), 0.f));
    *reinterpret_cast<uint4*>(&sB1[((0 * 4 + w) * 4 + q) * 64 + cl + 16 * g]) = r;
  }
  __syncthreads();  // buf0 visible

#pragma unroll
  for (int jc = 0; jc < 8; ++jc) {
    const int buf = jc & 1, nbuf = buf ^ 1;
    if (jc < 7) {  // prefetch chunk jc+1 (overlaps MFMA below)
      const int j1 = (jc + 1) * 128;
#pragma unroll
      for (int g = 0; g < 4; ++g) {
        pw[g] = *reinterpret_cast<const uint4*>(wbase + j1 + 8 * g);
        pe[g] = *reinterpret_cast<const uint4*>(ebase + j1 + 8 * g);
      }
    }
    // GEMM2' MFMA on buf
    const int ksg0 = jc * 4;
#pragma unroll
    for (int ks2 = 0; ks2 < 4; ++ks2) {
      s8v av[4], bv[4];
#pragma unroll
      for (int i = 0; i < 4; ++i)
        av[i] = w2F[(size_t)((w * 4 + i) * 32 + ksg0 + ks2) * 64 + lane];
#pragma unroll
      for (int ntp = 0; ntp < 4; ++ntp)
        bv[ntp] = sB1[((buf * 4 + ntp) * 4 + ks2) * 64 + lane];
#pragma unroll
      for (int i = 0; i < 4; ++i)
#pragma unroll
        for (int ntp = 0; ntp < 4; ++ntp)
          acc[i][ntp] = mfma16(av[i], bv[ntp], acc[i][ntp]);
    }
    if (jc < 7) {  // compute + store chunk jc+1 into nbuf
      const int j1 = (jc + 1) * 128;
#pragma unroll
      for (int g = 0; g < 4; ++g) {
        const uint4 hv =
            *reinterpret_cast<const uint4*>(&sHead[0][0] + hbase + j1 + 8 * g);
        uint4 r;
        r.x = pk2(fmaxf(blo(pw[g].x) + blo(pe[g].x) + blo(hv.x), 0.f),
                  fmaxf(bhi(pw[g].x) + bhi(pe[g].x) + bhi(hv.x), 0.f));
        r.y = pk2(fmaxf(blo(pw[g].y) + blo(pe[g].y) + blo(hv.y), 0.f),
                  fmaxf(bhi(pw[g].y) + bhi(pe[g].y) + bhi(hv.y), 0.f));
        r.z = pk2(fmaxf(blo(pw[g].z) + blo(pe[g].z) + blo(hv.z), 0.f),
                  fmaxf(bhi(pw[g].z) + bhi(pe[g].z) + bhi(hv.z), 0.f));
        r.w = pk2(fmaxf(blo(pw[g].w) + blo(pe[g].w) + blo(hv.w), 0.f),
                  fmaxf(bhi(pw[g].w) + bhi(pe[g].w) + bhi(hv.w), 0.f));
        *reinterpret_cast<uint4*>(
            &sB1[((nbuf * 4 + w) * 4 + q) * 64 + cl + 16 * g]) = r;
      }
    }
    __syncthreads();
  }

  // GEMM2' epilogue: X2^T = relu(acc + b2) -> B-frags for GEMM3'
#pragma unroll
  for (int i = 0; i < 4; ++i) {
    const int n2b = w * 64 + i * 16 + q * 4;
    const float4 bb = *reinterpret_cast<const float4*>(b2 + n2b);
    const int ks3 = n2b >> 5, g3 = (n2b >> 3) & 3, idx0 = n2b & 7;
#pragma unroll
    for (int ntp = 0; ntp < 4; ++ntp) {
      const unsigned u0 = pk2(fmaxf(acc[i][ntp][0] + bb.x, 0.f),
                              fmaxf(acc[i][ntp][1] + bb.y, 0.f));
      const unsigned u1 = pk2(fmaxf(acc[i][ntp][2] + bb.z, 0.f),
                              fmaxf(acc[i][ntp][3] + bb.w, 0.f));
      uint2 uu; uu.x = u0; uu.y = u1;
      *reinterpret_cast<uint2*>(
          sX2u + (((size_t)ntp * 8 + ks3) * 64 + cl + 16 * g3) * 8 + idx0) = uu;
    }
  }
  __syncthreads();

  // GEMM3': X3^T[c][p'] ; wave w -> c-tile w
  f32x4 acc3[4] = {};
#pragma unroll
  for (int ks3 = 0; ks3 < 8; ++ks3) {
    const s8v a = w3F[(size_t)(w * 8 + ks3) * 64 + lane];
#pragma unroll
    for (int ntp = 0; ntp < 4; ++ntp)
      acc3[ntp] = mfma16(a, sX2f[ntp][ks3][lane], acc3[ntp]);
  }
  __syncthreads();

  // zero conv frag region (24 KB)
  {
    uint4 z; z.x = z.y = z.z = z.w = 0;
    uint4* zp = reinterpret_cast<uint4*>(rgn);
#pragma unroll
    for (int i2 = 0; i2 < 6; ++i2) zp[t + 256 * i2] = z;
  }
  __syncthreads();

  // conv1' im2col frag writes
  {
    const int cb = 16 * w + q * 4;
    const float4 b3v = *reinterpret_cast<const float4*>(b3 + cb);
    const int gC = (cb >> 3) & 3, idx0 = cb & 7, ksb = cb >> 5;
#pragma unroll
    for (int ntp = 0; ntp < 4; ++ntp) {
      const int pp = ntp * 16 + cl, hd = pp >> 5, pos = pp & 31;
      const unsigned u0 = pk2(acc3[ntp][0] + b3v.x, acc3[ntp][1] + b3v.y);
      const unsigned u1 = pk2(acc3[ntp][2] + b3v.z, acc3[ntp][3] + b3v.w);
      uint2 uu; uu.x = u0; uu.y = u1;
#pragma unroll
      for (int tau = 0; tau < 3; ++tau) {
        const int pt = pos + 1 - tau;
        if ((unsigned)pt < 32u) {
          const int ppt = hd * 32 + pt;
          const int ks = 2 * tau + ksb;
          *reinterpret_cast<uint2*>(
              sX2u + (((size_t)(ppt >> 4) * 6 + ks) * 64 + (ppt & 15) + 16 * gC) * 8 +
              idx0) = uu;
        }
      }
    }
  }
  __syncthreads();

  // conv1' MFMA: Y1^T[o][p'] ; wave w -> o-tile w
  f32x4 accc[4] = {};
#pragma unroll
  for (int ks = 0; ks < 6; ++ks) {
    const s8v a = c1F[(size_t)(w * 6 + ks) * 64 + lane];
#pragma unroll
    for (int ntp = 0; ntp < 4; ++ntp)
      accc[ntp] = mfma16(a, sCv[ntp][ks][lane], accc[ntp]);
  }
  __syncthreads();

  // Y1^T -> fp32 LDS [64 o][68] with per-head zero pad cols (0,33,34,67)
  {
    const int o = t >> 2, pc = t & 3;
    const int colz = (pc == 0) ? 0 : (pc == 1) ? 33 : (pc == 2) ? 34 : 67;
    sY1[o * 68 + colz] = 0.f;
  }
  {
    const int ob = 16 * w + q * 4;
    const float4 cbv = *reinterpret_cast<const float4*>(c1b + ob);
#pragma unroll
    for (int ntp = 0; ntp < 4; ++ntp) {
      const int pp = ntp * 16 + cl, hd = pp >> 5, pos = pp & 31;
      const int col = hd * 34 + 1 + pos;
      sY1[(ob + 0) * 68 + col] = accc[ntp][0] + cbv.x;
      sY1[(ob + 1) * 68 + col] = accc[ntp][1] + cbv.y;
      sY1[(ob + 2) * 68 + col] = accc[ntp][2] + cbv.z;
      sY1[(ob + 3) * 68 + col] = accc[ntp][3] + cbv.w;
    }
  }
  __syncthreads();

  // conv2 (64ch*3tap -> 2) on VALU, K split 2 ways + shuffle reduce, scatter
  {
    const int kq = t & 1, c2 = (t >> 1) & 1, pp = t >> 2;
    const int hd = pp >> 5, pos = pp & 31, col = hd * 34 + 1 + pos;
    float a2 = 0.f;
    const float* wp = c2w + (size_t)(c2 * 64 + kq * 32) * 3;
    const float* yb = sY1 + (size_t)(kq * 32) * 68 + col;
#pragma unroll
    for (int o = 0; o < 32; ++o) {
      a2 += yb[o * 68 - 1] * wp[o * 3 + 0] + yb[o * 68] * wp[o * 3 + 1] +
            yb[o * 68 + 1] * wp[o * 3 + 2];
    }
    a2 += __shfl_xor(a2, 1, 64);
    if (kq == 0) {
      const int hidR = hd ? hidB : hidA;
      const int sR = hidR >> 5, offR = hidR & 31;
      const int rel = offR - pos;
      const bool ok = (c2 == 0) ? (rel >= 0) : (rel <= 0);
      out[(size_t)(h0 + hd) * 8192 + (size_t)(sR * 32 + pos) * 2 + c2] =
          ok ? (a2 + c2b[c2]) : NEG_SENT;
    }
  }
}

extern "C" void kernel_launch(void* const* d_in, const int* in_sizes, int n_in,
                              void* d_out, int out_size, void* d_ws,
                              size_t ws_size, hipStream_t stream) {
  const float* words = (const float*)d_in[1];
  const int* heads = (const int*)d_in[2];
  const float* emb = (const float*)d_in[3];
  const float* w1 = (const float*)d_in[4];
  const float* b1 = (const float*)d_in[5];
  const float* w2 = (const float*)d_in[6];
  const float* b2 = (const float*)d_in[7];
  const float* w3 = (const float*)d_in[8];
  const float* b3 = (const float*)d_in[9];
  const float* c1w = (const float*)d_in[10];
  const float* c1b = (const float*)d_in[11];
  const float* c2w = (const float*)d_in[12];
  const float* c2b = (const float*)d_in[13];
  float* out = (float*)d_out;

  char* ws = (char*)d_ws;
  unsigned short* embCb = (unsigned short*)ws;      ws += 128 * 1024 * 2;
  unsigned short* AWb = (unsigned short*)ws;        ws += 4096 * 2048 * 2;
  s8v* wordsF = (s8v*)ws;                           ws += 393216 * 16;
  s8v* w1F = (s8v*)ws;                              ws += 196608 * 16;
  s8v* w2F = (s8v*)ws;                              ws += 32768 * 16;
  s8v* w3F = (s8v*)ws;                              ws += 2048 * 16;
  s8v* c1F = (s8v*)ws;                              ws += 1536 * 16;

  k_prep1<<<2304, 256, 0, stream>>>(words, w1, wordsF, w1F);
  k_g1<<<782, 256, 0, stream>>>(wordsF, w1F, AWb, w1, b1, emb, w2, w3, c1w,
                                w2F, w3F, c1F, embCb);
  k_fused<<<1024, 256, 0, stream>>>(heads, AWb, embCb, w2F, b2, w3F, b3, c1F,
                                    c1b, c2w, c2b, out);
}